// Round 17
// baseline (482.816 us; speedup 1.0000x reference)
//
#include <hip/hip_runtime.h>

typedef __bf16 bf16_t;
typedef bf16_t bf16x8 __attribute__((ext_vector_type(8)));
typedef bf16_t bf16x4 __attribute__((ext_vector_type(4)));
typedef float f32x16 __attribute__((ext_vector_type(16)));
typedef float f32x4v __attribute__((ext_vector_type(4)));
typedef unsigned int u32;

#define DEVI __device__ __forceinline__

DEVI f32x16 zero16() {
  f32x16 z;
#pragma unroll
  for (int i = 0; i < 16; ++i) z[i] = 0.0f;
  return z;
}

DEVI void gload16(const bf16_t* g, const unsigned short* l) {
  __builtin_amdgcn_global_load_lds(
      (const __attribute__((address_space(1))) u32*)g,
      (__attribute__((address_space(3))) u32*)l, 16, 0, 0);
}

union U16B { bf16x8 v; uint4 u; unsigned short s[8]; };
union U4B  { bf16_t h[4]; uint2 u; };

// ---------------- prep: 4x W transpose->bf16  +  E pad ----------------
__global__ __launch_bounds__(256) void prep_kernel(
    const float* __restrict__ W0, const float* __restrict__ W1,
    const float* __restrict__ W2, const float* __restrict__ W3,
    bf16_t* __restrict__ T0, bf16_t* __restrict__ T1,
    bf16_t* __restrict__ T2, bf16_t* __restrict__ T3,
    const float* __restrict__ relE, bf16_t* __restrict__ Eb) {
  __shared__ float T[64][65];
  const int bid = blockIdx.x;
  const int tid = threadIdx.x;
  if (bid < 1024) {
    const int sel = bid >> 8;
    const float* W = sel == 0 ? W0 : sel == 1 ? W1 : sel == 2 ? W2 : W3;
    bf16_t* Wt = sel == 0 ? T0 : sel == 1 ? T1 : sel == 2 ? T2 : T3;
    const int bx = bid & 255;
    const int tx = bx & 15, ty = bx >> 4;
    const int k0 = ty * 64, n0 = tx * 64;
    {
      const int r = tid >> 4, c4 = (tid & 15) * 4;
#pragma unroll
      for (int rr = 0; rr < 64; rr += 16) {
        float4 v = *reinterpret_cast<const float4*>(&W[(size_t)(k0 + r + rr) * 1024 + n0 + c4]);
        T[r + rr][c4 + 0] = v.x; T[r + rr][c4 + 1] = v.y;
        T[r + rr][c4 + 2] = v.z; T[r + rr][c4 + 3] = v.w;
      }
    }
    __syncthreads();
    {
      const int r = tid >> 3, c8 = (tid & 7) * 8;
#pragma unroll
      for (int rr = 0; rr < 64; rr += 32) {
        U16B p;
#pragma unroll
        for (int i = 0; i < 8; ++i) p.v[i] = (bf16_t)T[c8 + i][r + rr];
        *reinterpret_cast<uint4*>(&Wt[(size_t)(n0 + r + rr) * 1024 + k0 + c8]) = p.u;
      }
    }
  } else {
    const int q = (bid - 1024) * 256 + tid;
    U4B p;
    if (q < 32752) {
      float4 v = *reinterpret_cast<const float4*>(&relE[(size_t)q * 4]);
      p.h[0] = (bf16_t)v.x; p.h[1] = (bf16_t)v.y; p.h[2] = (bf16_t)v.z; p.h[3] = (bf16_t)v.w;
    } else {
      p.h[0] = p.h[1] = p.h[2] = p.h[3] = (bf16_t)0.0f;
    }
    *reinterpret_cast<uint2*>(&Eb[(size_t)q * 4]) = p.u;
  }
}

#define ROWMAP(reg) (((reg) & 3) + 8 * ((reg) >> 2) + 4 * hi)

// ---------------- QKV GEMM: 256x256, BK=64, counted-vmcnt pipeline, A = f32 x ----
__global__ __launch_bounds__(512, 2) void gemm_qkv_kernel(
    const float* __restrict__ X0, const float* __restrict__ X1,
    const float* __restrict__ X2, const bf16_t* __restrict__ W0,
    const bf16_t* __restrict__ W1, const bf16_t* __restrict__ W2,
    const float* __restrict__ b0, const float* __restrict__ b1,
    const float* __restrict__ b2, bf16_t* __restrict__ O0,
    bf16_t* __restrict__ O1, bf16_t* __restrict__ O2) {
  __shared__ __align__(16) unsigned short As[2][256][64];
  __shared__ __align__(16) unsigned short Bs[2][256][64];
  const int f = blockIdx.x;
  const int fp = (f & 7) * 24 + (f >> 3);  // 192 blocks
  const int op = fp >> 6;
  const int r = fp & 63;
  const float* Xp = op == 0 ? X0 : op == 1 ? X1 : X2;
  const bf16_t* Wt = op == 0 ? W0 : op == 1 ? W1 : W2;
  const float* bias = op == 0 ? b0 : op == 1 ? b1 : b2;
  bf16_t* Out = op == 0 ? O0 : op == 1 ? O1 : O2;
  const int m0 = (r >> 2) * 256, n0 = (r & 3) * 256;
  const int tid = threadIdx.x;
  const int lane = tid & 63, wave = tid >> 6;
  const int hi = lane >> 5, ln = lane & 31;
  const int wr = wave >> 2, wc = wave & 3;
  const int srow = lane >> 3, scol = lane & 7;

  f32x16 acc[4][2];
#pragma unroll
  for (int rt = 0; rt < 4; ++rt) { acc[rt][0] = zero16(); acc[rt][1] = zero16(); }

  float4 fA[4][2];

#define ALOADR(kt)                                                                  \
  {                                                                                 \
    _Pragma("unroll")                                                               \
    for (int j = 0; j < 4; ++j) {                                                   \
      const int row = wave * 32 + j * 8 + srow;                                     \
      const float* src = &Xp[(size_t)(m0 + row) * 1024 + (kt) * 64 + scol * 8];     \
      fA[j][0] = *reinterpret_cast<const float4*>(src);                             \
      fA[j][1] = *reinterpret_cast<const float4*>(src + 4);                         \
    }                                                                               \
  }

#define ACVW(buf)                                                                   \
  {                                                                                 \
    _Pragma("unroll")                                                               \
    for (int j = 0; j < 4; ++j) {                                                   \
      const int row = wave * 32 + j * 8 + srow;                                     \
      U16B p;                                                                       \
      p.v[0] = (bf16_t)fA[j][0].x; p.v[1] = (bf16_t)fA[j][0].y;                     \
      p.v[2] = (bf16_t)fA[j][0].z; p.v[3] = (bf16_t)fA[j][0].w;                     \
      p.v[4] = (bf16_t)fA[j][1].x; p.v[5] = (bf16_t)fA[j][1].y;                     \
      p.v[6] = (bf16_t)fA[j][1].z; p.v[7] = (bf16_t)fA[j][1].w;                     \
      *reinterpret_cast<uint4*>(&As[buf][row][(scol ^ (row & 7)) * 8]) = p.u;       \
    }                                                                               \
  }

#define BGL(kt, buf)                                                                \
  {                                                                                 \
    _Pragma("unroll")                                                               \
    for (int j = 0; j < 4; ++j) {                                                   \
      const int rowbase = wave * 32 + j * 8;                                        \
      const int row = rowbase + srow;                                               \
      const int gc = scol ^ (row & 7);                                              \
      gload16(&Wt[(size_t)(n0 + row) * 1024 + (kt) * 64 + gc * 8],                  \
              &Bs[buf][rowbase][0]);                                                \
    }                                                                               \
  }

  ALOADR(0);
  asm volatile("s_waitcnt vmcnt(0)" ::: "memory");
  __builtin_amdgcn_sched_barrier(0);
  ACVW(0);
  BGL(0, 0);
  ALOADR(1);
  BGL(1, 1);

  for (int kt = 0; kt < 16; ++kt) {
    const int cur = kt & 1;
    if (kt < 15) {
      asm volatile("s_waitcnt vmcnt(12)" ::: "memory");
    } else {
      asm volatile("s_waitcnt vmcnt(0)" ::: "memory");
    }
    asm volatile("s_waitcnt lgkmcnt(0)" ::: "memory");
    __builtin_amdgcn_s_barrier();
    __builtin_amdgcn_sched_barrier(0);
#pragma unroll
    for (int kk = 0; kk < 4; ++kk) {
      const int ch = kk * 2 + hi;
      bf16x8 a[4], b[2];
#pragma unroll
      for (int rt = 0; rt < 4; ++rt) {
        const int ar = wr * 128 + rt * 32 + ln;
        a[rt] = *reinterpret_cast<const bf16x8*>(&As[cur][ar][(ch ^ (ar & 7)) * 8]);
      }
#pragma unroll
      for (int ct = 0; ct < 2; ++ct) {
        const int br = wc * 64 + ct * 32 + ln;
        b[ct] = *reinterpret_cast<const bf16x8*>(&Bs[cur][br][(ch ^ (br & 7)) * 8]);
      }
#pragma unroll
      for (int rt = 0; rt < 4; ++rt)
#pragma unroll
        for (int ct = 0; ct < 2; ++ct)
          acc[rt][ct] = __builtin_amdgcn_mfma_f32_32x32x16_bf16(a[rt], b[ct], acc[rt][ct], 0, 0, 0);
    }
    __builtin_amdgcn_sched_barrier(0);
    if (kt + 1 < 16) {
      asm volatile("s_waitcnt vmcnt(4)" ::: "memory");
      __builtin_amdgcn_sched_barrier(0);
      ACVW(cur ^ 1);
      if (kt + 2 < 16) ALOADR(kt + 2);
    }
    asm volatile("s_waitcnt lgkmcnt(0)" ::: "memory");
    __builtin_amdgcn_s_barrier();
    __builtin_amdgcn_sched_barrier(0);
    if (kt + 2 < 16) BGL(kt + 2, cur);
  }
#undef ALOADR
#undef ACVW
#undef BGL

#pragma unroll
  for (int ct = 0; ct < 2; ++ct) {
    const int nc = n0 + wc * 64 + ct * 32 + ln;
    const float bv = bias[nc];
    const int h = nc >> 6, d = nc & 63;
    if (op < 2) {
#pragma unroll
      for (int rt = 0; rt < 4; ++rt)
#pragma unroll
        for (int reg = 0; reg < 16; ++reg) {
          const int mr = m0 + wr * 128 + rt * 32 + ROWMAP(reg);
          const int b = mr >> 10, l = mr & 1023;
          Out[(((size_t)(b * 16 + h)) * 1024 + l) * 64 + d] =
              (bf16_t)(acc[rt][ct][reg] + bv);
        }
    } else {
#pragma unroll
      for (int rt = 0; rt < 4; ++rt)
#pragma unroll
        for (int g = 0; g < 4; ++g) {
          const int l4 = m0 + wr * 128 + rt * 32 + g * 8 + 4 * hi;
          const int b = l4 >> 10, ll = l4 & 1023;
          U4B p;
#pragma unroll
          for (int j = 0; j < 4; ++j) p.h[j] = (bf16_t)(acc[rt][ct][g * 4 + j] + bv);
          *reinterpret_cast<uint2*>(
              &Out[(((size_t)(b * 16 + h)) * 64 + d) * 1024 + ll]) = p.u;
        }
    }
  }
}

// ---------------- O-proj GEMM: 128x128 tile, 2-deep counted-vmcnt pipeline -------
__global__ __launch_bounds__(256) void gemm_o_kernel(
    const bf16_t* __restrict__ A0, const bf16_t* __restrict__ W0,
    const float* __restrict__ b0, float* __restrict__ O0) {
  __shared__ __align__(16) unsigned short As[2][128][64];
  __shared__ __align__(16) unsigned short Bs[2][128][64];
  const int f = blockIdx.x;
  const int fp = (f & 7) * 32 + (f >> 3);  // 256 blocks
  const int r = fp;
  const int m0 = (r >> 3) * 128, n0 = (r & 7) * 128;
  const int tid = threadIdx.x;
  const int lane = tid & 63, wave = tid >> 6;
  const int hi = lane >> 5, ln = lane & 31;
  const int wr = wave >> 1, wc = wave & 1;
  const int srow = lane >> 3, scol = lane & 7;

  f32x16 acc[2][2];
  acc[0][0] = zero16(); acc[0][1] = zero16();
  acc[1][0] = zero16(); acc[1][1] = zero16();

#define STAGE_O(kt, buf)                                                            \
  {                                                                                 \
    _Pragma("unroll")                                                               \
    for (int j = 0; j < 4; ++j) {                                                   \
      const int rowbase = wave * 32 + j * 8;                                        \
      const int row = rowbase + srow;                                               \
      const int gc = scol ^ (row & 7);                                              \
      gload16(&A0[(size_t)(m0 + row) * 1024 + (kt) * 64 + gc * 8],                  \
              &As[buf][rowbase][0]);                                                \
      gload16(&W0[(size_t)(n0 + row) * 1024 + (kt) * 64 + gc * 8],                  \
              &Bs[buf][rowbase][0]);                                                \
    }                                                                               \
  }

  STAGE_O(0, 0);
  STAGE_O(1, 1);

  for (int kt = 0; kt < 16; ++kt) {
    const int cur = kt & 1;
    if (kt < 15) {
      asm volatile("s_waitcnt vmcnt(8)" ::: "memory");
    } else {
      asm volatile("s_waitcnt vmcnt(0)" ::: "memory");
    }
    __builtin_amdgcn_s_barrier();
    __builtin_amdgcn_sched_barrier(0);
#pragma unroll
    for (int kk = 0; kk < 4; ++kk) {
      const int ch = kk * 2 + hi;
      const int ar0 = wr * 64 + ln, ar1 = ar0 + 32;
      const int br0 = wc * 64 + ln, br1 = br0 + 32;
      bf16x8 a0 = *reinterpret_cast<const bf16x8*>(&As[cur][ar0][(ch ^ (ar0 & 7)) * 8]);
      bf16x8 a1 = *reinterpret_cast<const bf16x8*>(&As[cur][ar1][(ch ^ (ar1 & 7)) * 8]);
      bf16x8 bb0 = *reinterpret_cast<const bf16x8*>(&Bs[cur][br0][(ch ^ (br0 & 7)) * 8]);
      bf16x8 bb1 = *reinterpret_cast<const bf16x8*>(&Bs[cur][br1][(ch ^ (br1 & 7)) * 8]);
      acc[0][0] = __builtin_amdgcn_mfma_f32_32x32x16_bf16(a0, bb0, acc[0][0], 0, 0, 0);
      acc[0][1] = __builtin_amdgcn_mfma_f32_32x32x16_bf16(a0, bb1, acc[0][1], 0, 0, 0);
      acc[1][0] = __builtin_amdgcn_mfma_f32_32x32x16_bf16(a1, bb0, acc[1][0], 0, 0, 0);
      acc[1][1] = __builtin_amdgcn_mfma_f32_32x32x16_bf16(a1, bb1, acc[1][1], 0, 0, 0);
    }
    __builtin_amdgcn_sched_barrier(0);
    __builtin_amdgcn_s_barrier();
    __builtin_amdgcn_sched_barrier(0);
    if (kt + 2 < 16) STAGE_O(kt + 2, cur);
  }
#undef STAGE_O

#pragma unroll
  for (int cb = 0; cb < 2; ++cb) {
    const int nc = n0 + wc * 64 + cb * 32 + ln;
    const float bv = b0[nc];
#pragma unroll
    for (int rb = 0; rb < 2; ++rb)
#pragma unroll
      for (int reg = 0; reg < 16; ++reg) {
        const int mr = m0 + wr * 64 + rb * 32 + ROWMAP(reg);
        O0[(size_t)mr * 1024 + nc] = acc[rb][cb][reg] + bv;
      }
  }
}

// ---------------- fused attention: 16x16-fragment, 16-wave, full-occupancy -------
// R17: 4096 blocks x 1024 thr (16 waves). Block = (bh, 16 q-rows). Wave wv owns
// cols [64wv, 64wv+64). mfma_f32_16x16x32_bf16 (acc f32x4) shrinks per-wave state
// to ~55 VGPR -> __launch_bounds__(1024,8) forces <=64 -> 2 blocks/CU, 32 waves/CU
// (100% occupancy vs 41%). Bias via rolling 16-row Tcur/Tpre + provider-merged
// gather at 16-granularity: j = l-r+15; j<16 -> Tcur[col j] else Tpre[col j-16];
// src lane (lane&48)|(j&15); provider sel (col >= l). E-window rows l0-r0+1008+j
// all within existing padded Eb[2048]. Strip[16][1024] bf16 (32KB) chunk-XOR
// swizzled (chunk ^ (row&7)); all strip accesses same-wave -> no barrier.
// S1: rstat; cred[16][16][64] f32 (64KB, aliases dead strip); S2; final reduce.
__global__ __launch_bounds__(1024, 8) void attn_kernel(
    const bf16_t* __restrict__ q, const bf16_t* __restrict__ k,
    const bf16_t* __restrict__ vt, const bf16_t* __restrict__ E,
    float* __restrict__ probs, bf16_t* __restrict__ ctx) {
  __shared__ __align__(16) float cred[16][16][64];   // 64KB; first 32KB aliases strip
  __shared__ float rstat[16][17];
  unsigned short* strip = reinterpret_cast<unsigned short*>(&cred[0][0][0]);  // [16][1024]
  const int f = blockIdx.x;
  const int fp = (f & 7) * 512 + (f >> 3);   // 4096 blocks
  const int bh = fp >> 6;
  const int l0 = (fp & 63) * 16;
  const int tid = threadIdx.x;
  const int lane = tid & 63, wv = tid >> 6;  // 16 waves
  const int lr = lane & 15;                  // low nibble: row (A/C) or col (B)
  const int lg = lane >> 4;                  // k-group 0..3
  const bf16_t* qb = q + (size_t)bh * 1024 * 64;
  const bf16_t* kb = k + (size_t)bh * 1024 * 64;
  const bf16_t* vb = vt + (size_t)bh * 64 * 1024;
  const int c0 = wv * 64;                    // wave's column base
  const int eb0 = l0 - c0 + 1008;            // E-row base for t=0 (always >= 0)

  // Q A-frags: row = lr, k = d-slice*32 + lg*8
  bf16x8 qf0 = *reinterpret_cast<const bf16x8*>(&qb[(size_t)(l0 + lr) * 64 + lg * 8]);
  bf16x8 qf1 = *reinterpret_cast<const bf16x8*>(&qb[(size_t)(l0 + lr) * 64 + 32 + lg * 8]);

  // prologue Tpre = Q . E rows [eb0+16, eb0+32)
  f32x4v tpre = {0.0f, 0.0f, 0.0f, 0.0f};
  {
    bf16x8 e0 = *reinterpret_cast<const bf16x8*>(&E[(size_t)(eb0 + 16 + lr) * 64 + lg * 8]);
    bf16x8 e1 = *reinterpret_cast<const bf16x8*>(&E[(size_t)(eb0 + 16 + lr) * 64 + 32 + lg * 8]);
    tpre = __builtin_amdgcn_mfma_f32_16x16x32_bf16(qf0, e0, tpre, 0, 0, 0);
    tpre = __builtin_amdgcn_mfma_f32_16x16x32_bf16(qf1, e1, tpre, 0, 0, 0);
  }

#pragma unroll
  for (int t = 0; t < 4; ++t) {
    const int r0 = c0 + 16 * t;
    const int eb = eb0 - 16 * t;
    f32x4v acc = {0.0f, 0.0f, 0.0f, 0.0f};
    f32x4v tcur = {0.0f, 0.0f, 0.0f, 0.0f};
    __builtin_amdgcn_s_setprio(1);
    {
      bf16x8 kf0 = *reinterpret_cast<const bf16x8*>(&kb[(size_t)(r0 + lr) * 64 + lg * 8]);
      bf16x8 kf1 = *reinterpret_cast<const bf16x8*>(&kb[(size_t)(r0 + lr) * 64 + 32 + lg * 8]);
      acc = __builtin_amdgcn_mfma_f32_16x16x32_bf16(qf0, kf0, acc, 0, 0, 0);
      acc = __builtin_amdgcn_mfma_f32_16x16x32_bf16(qf1, kf1, acc, 0, 0, 0);
      bf16x8 e0 = *reinterpret_cast<const bf16x8*>(&E[(size_t)(eb + lr) * 64 + lg * 8]);
      bf16x8 e1 = *reinterpret_cast<const bf16x8*>(&E[(size_t)(eb + lr) * 64 + 32 + lg * 8]);
      tcur = __builtin_amdgcn_mfma_f32_16x16x32_bf16(qf0, e0, tcur, 0, 0, 0);
      tcur = __builtin_amdgcn_mfma_f32_16x16x32_bf16(qf1, e1, tcur, 0, 0, 0);
    }
    __builtin_amdgcn_s_setprio(0);
    // provider-merged gather + exp + strip write (rows l = lg*4+reg, col r = lr)
#pragma unroll
    for (int reg = 0; reg < 4; ++reg) {
      const int l = lg * 4 + reg;
      const int src = (lane & 48) | ((l - lr + 15) & 15);
      const float sel = (lr >= l) ? tcur[reg] : tpre[reg];
      const float sv = acc[reg] + __shfl(sel, src, 64);
      union { bf16_t h; unsigned short u; } cv;
      cv.h = (bf16_t)exp2f(sv * 0.1803368801f);
      const int colg = r0 + lr;  // global col (within wave's 64)
      strip[(size_t)l * 1024 + (colg ^ ((l & 7) << 3))] = cv.u;
    }
    tpre = tcur;
  }

  // ---- pull own probs + rowsum (same-wave strip reads; lane = (row lr, quarter lg)) ----
  bf16x8 pr0, pr1;
  float inv;
  {
    const int ch0 = (8 * wv + 2 * lg + 0) ^ (lr & 7);
    const int ch1 = (8 * wv + 2 * lg + 1) ^ (lr & 7);
    pr0 = *reinterpret_cast<const bf16x8*>(&strip[(size_t)lr * 1024 + ch0 * 8]);
    pr1 = *reinterpret_cast<const bf16x8*>(&strip[(size_t)lr * 1024 + ch1 * 8]);
    float s = 0.0f;
#pragma unroll
    for (int e = 0; e < 8; ++e) s += (float)pr0[e] + (float)pr1[e];
    s += __shfl_xor(s, 16, 64);
    s += __shfl_xor(s, 32, 64);
    if (lane < 16) rstat[lr][wv] = s;
  }

  // ---- PV: pv[dt] (16x16 d-tiles), A = P strip rows, B = V[d][r] ----
  f32x4v pv0 = {0,0,0,0}, pv1 = {0,0,0,0}, pv2 = {0,0,0,0}, pv3 = {0,0,0,0};
  {
    const int cha = (8 * wv + 0 * 4 + lg) ^ (lr & 7);
    const int chb = (8 * wv + 1 * 4 + lg) ^ (lr & 7);
    bf16x8 pa0 = *reinterpret_cast<const bf16x8*>(&strip[(size_t)lr * 1024 + cha * 8]);
    bf16x8 pa1 = *reinterpret_cast<const bf16x8*>(&strip[(size_t)lr * 1024 + chb * 8]);
    __builtin_amdgcn_s_setprio(1);
#pragma unroll
    for (int dt = 0; dt < 4; ++dt) {
      bf16x8 v0 = *reinterpret_cast<const bf16x8*>(
          &vb[(size_t)(dt * 16 + lr) * 1024 + c0 + lg * 8]);
      bf16x8 v1 = *reinterpret_cast<const bf16x8*>(
          &vb[(size_t)(dt * 16 + lr) * 1024 + c0 + 32 + lg * 8]);
      f32x4v* pvp = dt == 0 ? &pv0 : dt == 1 ? &pv1 : dt == 2 ? &pv2 : &pv3;
      *pvp = __builtin_amdgcn_mfma_f32_16x16x32_bf16(pa0, v0, *pvp, 0, 0, 0);
      *pvp = __builtin_amdgcn_mfma_f32_16x16x32_bf16(pa1, v1, *pvp, 0, 0, 0);
    }
    __builtin_amdgcn_s_setprio(0);
  }

  __syncthreads();  // S1: rstat ready; all strip reads retired (cred may alias)

  {
    float s = 0.0f;
#pragma unroll
    for (int w = 0; w < 16; ++w) s += rstat[lr][w];
    inv = 1.0f / s;
  }

  // ---- cred write: wave wv slot; pv element (row = lg*4+reg, d = dt*16+lr) ----
#pragma unroll
  for (int reg = 0; reg < 4; ++reg) {
    const int row = lg * 4 + reg;
    cred[wv][row][0 * 16 + lr] = pv0[reg];
    cred[wv][row][1 * 16 + lr] = pv1[reg];
    cred[wv][row][2 * 16 + lr] = pv2[reg];
    cred[wv][row][3 * 16 + lr] = pv3[reg];
  }
  __syncthreads();  // S2: cred complete

  // ---- final ctx: thread -> (row = tid>>6, d = tid&63); sum 16 slots ----
  {
    const int row = tid >> 6, d = tid & 63;
    float a = 0.0f;
#pragma unroll
    for (int s16 = 0; s16 < 16; ++s16) a += cred[s16][row][d];
    float rs = 0.0f;
#pragma unroll
    for (int w = 0; w < 16; ++w) rs += rstat[row][w];
    const int b = bh >> 4, h = bh & 15;
    ctx[((((size_t)b * 1024) + l0 + row) * 16 + h) * 64 + d] = (bf16_t)(a / rs);
  }

  // ---- probs stores LAST (regs pr0/pr1; true cols from swizzled chunks) ----
  {
    float* pb = probs + ((size_t)bh * 1024 + l0) * 1024 + (size_t)lr * 1024;
    const int tc0 = (8 * wv + 2 * lg + 0) * 8;  // true col base of pr0
    const int tc1 = (8 * wv + 2 * lg + 1) * 8;  // true col base of pr1
    f32x4v o;
    o[0] = (float)pr0[0] * inv; o[1] = (float)pr0[1] * inv;
    o[2] = (float)pr0[2] * inv; o[3] = (float)pr0[3] * inv;
    __builtin_nontemporal_store(o, reinterpret_cast<f32x4v*>(&pb[tc0]));
    o[0] = (float)pr0[4] * inv; o[1] = (float)pr0[5] * inv;
    o[2] = (float)pr0[6] * inv; o[3] = (float)pr0[7] * inv;
    __builtin_nontemporal_store(o, reinterpret_cast<f32x4v*>(&pb[tc0 + 4]));
    o[0] = (float)pr1[0] * inv; o[1] = (float)pr1[1] * inv;
    o[2] = (float)pr1[2] * inv; o[3] = (float)pr1[3] * inv;
    __builtin_nontemporal_store(o, reinterpret_cast<f32x4v*>(&pb[tc1]));
    o[0] = (float)pr1[4] * inv; o[1] = (float)pr1[5] * inv;
    o[2] = (float)pr1[6] * inv; o[3] = (float)pr1[7] * inv;
    __builtin_nontemporal_store(o, reinterpret_cast<f32x4v*>(&pb[tc1 + 4]));
  }
}

// ---------------- launch ---------------------------------------------------------
extern "C" void kernel_launch(void* const* d_in, const int* in_sizes, int n_in,
                              void* d_out, int out_size, void* d_ws, size_t ws_size,
                              hipStream_t stream) {
  const float* xq = (const float*)d_in[0];
  const float* xk = (const float*)d_in[1];
  const float* xv = (const float*)d_in[2];
  const float* Wq = (const float*)d_in[3];
  const float* bq = (const float*)d_in[4];
  const float* Wk = (const float*)d_in[5];
  const float* bk = (const float*)d_in[6];
  const float* Wv = (const float*)d_in[7];
  const float* bv = (const float*)d_in[8];
  const float* Wo = (const float*)d_in[9];
  const float* bo = (const float*)d_in[10];
  const float* relE = (const float*)d_in[11];

  char* ws = (char*)d_ws;
  const size_t MB2 = 1u << 21;
  bf16_t* WtQ = (bf16_t*)(ws + 0 * MB2);
  bf16_t* WtK = (bf16_t*)(ws + 1 * MB2);
  bf16_t* WtV = (bf16_t*)(ws + 2 * MB2);
  bf16_t* WtO = (bf16_t*)(ws + 3 * MB2);
  bf16_t* Eb  = (bf16_t*)(ws + 4 * MB2);
  bf16_t* qb  = (bf16_t*)(ws + 4 * MB2 + (1u << 19));
  bf16_t* kb  = qb + (size_t)4 * 16 * 1024 * 64;
  bf16_t* vtb = kb + (size_t)4 * 16 * 1024 * 64;
  bf16_t* ctxb = vtb + (size_t)4 * 16 * 1024 * 64;

  float* outp = (float*)d_out;
  float* probs = outp + (size_t)4 * 1024 * 1024;

  prep_kernel<<<1152, 256, 0, stream>>>(Wq, Wk, Wv, Wo, WtQ, WtK, WtV, WtO,
                                        relE, Eb);
  gemm_qkv_kernel<<<192, 512, 0, stream>>>(xq, xk, xv, WtQ, WtK, WtV,
                                           bq, bk, bv, qb, kb, vtb);
  attn_kernel<<<4096, 1024, 0, stream>>>(qb, kb, vtb, Eb, probs, ctxb);
  gemm_o_kernel<<<256, 256, 0, stream>>>(ctxb, WtO, bo, outp);
}

// Round 18
// 190.613 us; speedup vs baseline: 2.5330x; 2.5330x over previous
//
#include <hip/hip_runtime.h>

typedef __bf16 bf16_t;
typedef bf16_t bf16x8 __attribute__((ext_vector_type(8)));
typedef bf16_t bf16x4 __attribute__((ext_vector_type(4)));
typedef float f32x16 __attribute__((ext_vector_type(16)));
typedef float f32x4v __attribute__((ext_vector_type(4)));
typedef unsigned int u32;

#define DEVI __device__ __forceinline__

DEVI f32x16 zero16() {
  f32x16 z;
#pragma unroll
  for (int i = 0; i < 16; ++i) z[i] = 0.0f;
  return z;
}

DEVI void gload16(const bf16_t* g, const unsigned short* l) {
  __builtin_amdgcn_global_load_lds(
      (const __attribute__((address_space(1))) u32*)g,
      (__attribute__((address_space(3))) u32*)l, 16, 0, 0);
}

union U16B { bf16x8 v; uint4 u; unsigned short s[8]; };
union U4B  { bf16_t h[4]; uint2 u; };

// ---------------- prep: 4x W transpose->bf16  +  E pad (x-convert fused into QKV) --
__global__ __launch_bounds__(256) void prep_kernel(
    const float* __restrict__ W0, const float* __restrict__ W1,
    const float* __restrict__ W2, const float* __restrict__ W3,
    bf16_t* __restrict__ T0, bf16_t* __restrict__ T1,
    bf16_t* __restrict__ T2, bf16_t* __restrict__ T3,
    const float* __restrict__ relE, bf16_t* __restrict__ Eb) {
  __shared__ float T[64][65];
  const int bid = blockIdx.x;
  const int tid = threadIdx.x;
  if (bid < 1024) {
    const int sel = bid >> 8;
    const float* W = sel == 0 ? W0 : sel == 1 ? W1 : sel == 2 ? W2 : W3;
    bf16_t* Wt = sel == 0 ? T0 : sel == 1 ? T1 : sel == 2 ? T2 : T3;
    const int bx = bid & 255;
    const int tx = bx & 15, ty = bx >> 4;
    const int k0 = ty * 64, n0 = tx * 64;
    {
      const int r = tid >> 4, c4 = (tid & 15) * 4;
#pragma unroll
      for (int rr = 0; rr < 64; rr += 16) {
        float4 v = *reinterpret_cast<const float4*>(&W[(size_t)(k0 + r + rr) * 1024 + n0 + c4]);
        T[r + rr][c4 + 0] = v.x; T[r + rr][c4 + 1] = v.y;
        T[r + rr][c4 + 2] = v.z; T[r + rr][c4 + 3] = v.w;
      }
    }
    __syncthreads();
    {
      const int r = tid >> 3, c8 = (tid & 7) * 8;
#pragma unroll
      for (int rr = 0; rr < 64; rr += 32) {
        U16B p;
#pragma unroll
        for (int i = 0; i < 8; ++i) p.v[i] = (bf16_t)T[c8 + i][r + rr];
        *reinterpret_cast<uint4*>(&Wt[(size_t)(n0 + r + rr) * 1024 + k0 + c8]) = p.u;
      }
    }
  } else {
    // E pad: 32768 quads over 128 blocks x 256 threads (one quad each)
    const int q = (bid - 1024) * 256 + tid;
    U4B p;
    if (q < 32752) {
      float4 v = *reinterpret_cast<const float4*>(&relE[(size_t)q * 4]);
      p.h[0] = (bf16_t)v.x; p.h[1] = (bf16_t)v.y; p.h[2] = (bf16_t)v.z; p.h[3] = (bf16_t)v.w;
    } else {
      p.h[0] = p.h[1] = p.h[2] = p.h[3] = (bf16_t)0.0f;
    }
    *reinterpret_cast<uint2*>(&Eb[(size_t)q * 4]) = p.u;
  }
}

#define ROWMAP(reg) (((reg) & 3) + 8 * ((reg) >> 2) + 4 * hi)

// ---------------- QKV GEMM: 256x256, BK=64, counted-vmcnt pipeline, A = f32 x ----
// (R13 win: fused f32->bf16 A staging; FIFO vmcnt [B(kt)4, A(kt+1)8, B(kt+1)4])
__global__ __launch_bounds__(512, 2) void gemm_qkv_kernel(
    const float* __restrict__ X0, const float* __restrict__ X1,
    const float* __restrict__ X2, const bf16_t* __restrict__ W0,
    const bf16_t* __restrict__ W1, const bf16_t* __restrict__ W2,
    const float* __restrict__ b0, const float* __restrict__ b1,
    const float* __restrict__ b2, bf16_t* __restrict__ O0,
    bf16_t* __restrict__ O1, bf16_t* __restrict__ O2) {
  __shared__ __align__(16) unsigned short As[2][256][64];
  __shared__ __align__(16) unsigned short Bs[2][256][64];
  const int f = blockIdx.x;
  const int fp = (f & 7) * 24 + (f >> 3);  // 192 blocks, 192%8==0
  const int op = fp >> 6;
  const int r = fp & 63;
  const float* Xp = op == 0 ? X0 : op == 1 ? X1 : X2;
  const bf16_t* Wt = op == 0 ? W0 : op == 1 ? W1 : W2;
  const float* bias = op == 0 ? b0 : op == 1 ? b1 : b2;
  bf16_t* Out = op == 0 ? O0 : op == 1 ? O1 : O2;
  const int m0 = (r >> 2) * 256, n0 = (r & 3) * 256;
  const int tid = threadIdx.x;
  const int lane = tid & 63, wave = tid >> 6;
  const int hi = lane >> 5, ln = lane & 31;
  const int wr = wave >> 2, wc = wave & 3;       // 2 x 4 wave grid
  const int srow = lane >> 3, scol = lane & 7;

  f32x16 acc[4][2];
#pragma unroll
  for (int rt = 0; rt < 4; ++rt) { acc[rt][0] = zero16(); acc[rt][1] = zero16(); }

  float4 fA[4][2];  // staged A f32 (tile kt+1): 4 row-groups x 8 f32

#define ALOADR(kt)                                                                  \
  {                                                                                 \
    _Pragma("unroll")                                                               \
    for (int j = 0; j < 4; ++j) {                                                   \
      const int row = wave * 32 + j * 8 + srow;                                     \
      const float* src = &Xp[(size_t)(m0 + row) * 1024 + (kt) * 64 + scol * 8];     \
      fA[j][0] = *reinterpret_cast<const float4*>(src);                             \
      fA[j][1] = *reinterpret_cast<const float4*>(src + 4);                         \
    }                                                                               \
  }

#define ACVW(buf)                                                                   \
  {                                                                                 \
    _Pragma("unroll")                                                               \
    for (int j = 0; j < 4; ++j) {                                                   \
      const int row = wave * 32 + j * 8 + srow;                                     \
      U16B p;                                                                       \
      p.v[0] = (bf16_t)fA[j][0].x; p.v[1] = (bf16_t)fA[j][0].y;                     \
      p.v[2] = (bf16_t)fA[j][0].z; p.v[3] = (bf16_t)fA[j][0].w;                     \
      p.v[4] = (bf16_t)fA[j][1].x; p.v[5] = (bf16_t)fA[j][1].y;                     \
      p.v[6] = (bf16_t)fA[j][1].z; p.v[7] = (bf16_t)fA[j][1].w;                     \
      *reinterpret_cast<uint4*>(&As[buf][row][(scol ^ (row & 7)) * 8]) = p.u;       \
    }                                                                               \
  }

#define BGL(kt, buf)                                                                \
  {                                                                                 \
    _Pragma("unroll")                                                               \
    for (int j = 0; j < 4; ++j) {                                                   \
      const int rowbase = wave * 32 + j * 8;                                        \
      const int row = rowbase + srow;                                               \
      const int gc = scol ^ (row & 7);                                              \
      gload16(&Wt[(size_t)(n0 + row) * 1024 + (kt) * 64 + gc * 8],                  \
              &Bs[buf][rowbase][0]);                                                \
    }                                                                               \
  }

  // prologue: outstanding order must end as [B(0)4, A(1)8, B(1)4]
  ALOADR(0);
  asm volatile("s_waitcnt vmcnt(0)" ::: "memory");
  __builtin_amdgcn_sched_barrier(0);
  ACVW(0);
  BGL(0, 0);
  ALOADR(1);
  BGL(1, 1);

  for (int kt = 0; kt < 16; ++kt) {
    const int cur = kt & 1;
    if (kt < 15) {
      asm volatile("s_waitcnt vmcnt(12)" ::: "memory");  // B(kt) landed
    } else {
      asm volatile("s_waitcnt vmcnt(0)" ::: "memory");
    }
    asm volatile("s_waitcnt lgkmcnt(0)" ::: "memory");   // publish A ds_writes
    __builtin_amdgcn_s_barrier();
    __builtin_amdgcn_sched_barrier(0);
#pragma unroll
    for (int kk = 0; kk < 4; ++kk) {
      const int ch = kk * 2 + hi;
      bf16x8 a[4], b[2];
#pragma unroll
      for (int rt = 0; rt < 4; ++rt) {
        const int ar = wr * 128 + rt * 32 + ln;
        a[rt] = *reinterpret_cast<const bf16x8*>(&As[cur][ar][(ch ^ (ar & 7)) * 8]);
      }
#pragma unroll
      for (int ct = 0; ct < 2; ++ct) {
        const int br = wc * 64 + ct * 32 + ln;
        b[ct] = *reinterpret_cast<const bf16x8*>(&Bs[cur][br][(ch ^ (br & 7)) * 8]);
      }
#pragma unroll
      for (int rt = 0; rt < 4; ++rt)
#pragma unroll
        for (int ct = 0; ct < 2; ++ct)
          acc[rt][ct] = __builtin_amdgcn_mfma_f32_32x32x16_bf16(a[rt], b[ct], acc[rt][ct], 0, 0, 0);
    }
    __builtin_amdgcn_sched_barrier(0);
    if (kt + 1 < 16) {
      asm volatile("s_waitcnt vmcnt(4)" ::: "memory");   // A(kt+1) regs landed
      __builtin_amdgcn_sched_barrier(0);
      ACVW(cur ^ 1);                                     // tile kt+1 A -> its buffer
      if (kt + 2 < 16) ALOADR(kt + 2);                   // refill fA
    }
    asm volatile("s_waitcnt lgkmcnt(0)" ::: "memory");   // ds_writes committed
    __builtin_amdgcn_s_barrier();                        // trailing: buf[cur] reads retired
    __builtin_amdgcn_sched_barrier(0);
    if (kt + 2 < 16) BGL(kt + 2, cur);                   // B tile kt+2 into buf[cur]
  }
#undef ALOADR
#undef ACVW
#undef BGL

  // ---- epilogue: bias + scatter to Q/K [B,H,L,D] or V [B,H,D,L] ----
#pragma unroll
  for (int ct = 0; ct < 2; ++ct) {
    const int nc = n0 + wc * 64 + ct * 32 + ln;
    const float bv = bias[nc];
    const int h = nc >> 6, d = nc & 63;
    if (op < 2) {
#pragma unroll
      for (int rt = 0; rt < 4; ++rt)
#pragma unroll
        for (int reg = 0; reg < 16; ++reg) {
          const int mr = m0 + wr * 128 + rt * 32 + ROWMAP(reg);
          const int b = mr >> 10, l = mr & 1023;
          Out[(((size_t)(b * 16 + h)) * 1024 + l) * 64 + d] =
              (bf16_t)(acc[rt][ct][reg] + bv);
        }
    } else {
#pragma unroll
      for (int rt = 0; rt < 4; ++rt)
#pragma unroll
        for (int g = 0; g < 4; ++g) {
          const int l4 = m0 + wr * 128 + rt * 32 + g * 8 + 4 * hi;
          const int b = l4 >> 10, ll = l4 & 1023;
          U4B p;
#pragma unroll
          for (int j = 0; j < 4; ++j) p.h[j] = (bf16_t)(acc[rt][ct][g * 4 + j] + bv);
          *reinterpret_cast<uint2*>(
              &Out[(((size_t)(b * 16 + h)) * 64 + d) * 1024 + ll]) = p.u;
        }
    }
  }
}

// ---------------- O-proj GEMM: 128x128 tile, 2-deep counted-vmcnt pipeline -------
__global__ __launch_bounds__(256) void gemm_o_kernel(
    const bf16_t* __restrict__ A0, const bf16_t* __restrict__ W0,
    const float* __restrict__ b0, float* __restrict__ O0) {
  __shared__ __align__(16) unsigned short As[2][128][64];
  __shared__ __align__(16) unsigned short Bs[2][128][64];
  const int f = blockIdx.x;
  const int fp = (f & 7) * 32 + (f >> 3);  // 256 blocks
  const int r = fp;
  const int m0 = (r >> 3) * 128, n0 = (r & 7) * 128;
  const int tid = threadIdx.x;
  const int lane = tid & 63, wave = tid >> 6;
  const int hi = lane >> 5, ln = lane & 31;
  const int wr = wave >> 1, wc = wave & 1;
  const int srow = lane >> 3, scol = lane & 7;

  f32x16 acc[2][2];
  acc[0][0] = zero16(); acc[0][1] = zero16();
  acc[1][0] = zero16(); acc[1][1] = zero16();

#define STAGE_O(kt, buf)                                                            \
  {                                                                                 \
    _Pragma("unroll")                                                               \
    for (int j = 0; j < 4; ++j) {                                                   \
      const int rowbase = wave * 32 + j * 8;                                        \
      const int row = rowbase + srow;                                               \
      const int gc = scol ^ (row & 7);                                              \
      gload16(&A0[(size_t)(m0 + row) * 1024 + (kt) * 64 + gc * 8],                  \
              &As[buf][rowbase][0]);                                                \
      gload16(&W0[(size_t)(n0 + row) * 1024 + (kt) * 64 + gc * 8],                  \
              &Bs[buf][rowbase][0]);                                                \
    }                                                                               \
  }

  STAGE_O(0, 0);
  STAGE_O(1, 1);

  for (int kt = 0; kt < 16; ++kt) {
    const int cur = kt & 1;
    if (kt < 15) {
      asm volatile("s_waitcnt vmcnt(8)" ::: "memory");
    } else {
      asm volatile("s_waitcnt vmcnt(0)" ::: "memory");
    }
    __builtin_amdgcn_s_barrier();
    __builtin_amdgcn_sched_barrier(0);
#pragma unroll
    for (int kk = 0; kk < 4; ++kk) {
      const int ch = kk * 2 + hi;
      const int ar0 = wr * 64 + ln, ar1 = ar0 + 32;
      const int br0 = wc * 64 + ln, br1 = br0 + 32;
      bf16x8 a0 = *reinterpret_cast<const bf16x8*>(&As[cur][ar0][(ch ^ (ar0 & 7)) * 8]);
      bf16x8 a1 = *reinterpret_cast<const bf16x8*>(&As[cur][ar1][(ch ^ (ar1 & 7)) * 8]);
      bf16x8 bb0 = *reinterpret_cast<const bf16x8*>(&Bs[cur][br0][(ch ^ (br0 & 7)) * 8]);
      bf16x8 bb1 = *reinterpret_cast<const bf16x8*>(&Bs[cur][br1][(ch ^ (br1 & 7)) * 8]);
      acc[0][0] = __builtin_amdgcn_mfma_f32_32x32x16_bf16(a0, bb0, acc[0][0], 0, 0, 0);
      acc[0][1] = __builtin_amdgcn_mfma_f32_32x32x16_bf16(a0, bb1, acc[0][1], 0, 0, 0);
      acc[1][0] = __builtin_amdgcn_mfma_f32_32x32x16_bf16(a1, bb0, acc[1][0], 0, 0, 0);
      acc[1][1] = __builtin_amdgcn_mfma_f32_32x32x16_bf16(a1, bb1, acc[1][1], 0, 0, 0);
    }
    __builtin_amdgcn_sched_barrier(0);
    __builtin_amdgcn_s_barrier();
    __builtin_amdgcn_sched_barrier(0);
    if (kt + 2 < 16) STAGE_O(kt + 2, cur);
  }
#undef STAGE_O

#pragma unroll
  for (int cb = 0; cb < 2; ++cb) {
    const int nc = n0 + wc * 64 + cb * 32 + ln;
    const float bv = b0[nc];
#pragma unroll
    for (int rb = 0; rb < 2; ++rb)
#pragma unroll
      for (int reg = 0; reg < 16; ++reg) {
        const int mr = m0 + wr * 64 + rb * 32 + ROWMAP(reg);
        O0[(size_t)mr * 1024 + nc] = acc[rb][cb][reg] + bv;
      }
  }
}

// ---------------- fused attention (exact R4 anchor; R13 config = session best) ---
__global__ __launch_bounds__(512, 4) void attn_kernel(
    const bf16_t* __restrict__ q, const bf16_t* __restrict__ k,
    const bf16_t* __restrict__ vt, const bf16_t* __restrict__ E,
    float* __restrict__ probs, bf16_t* __restrict__ ctx) {
  __shared__ __align__(16) unsigned short Pbuf[8][32][128];  // 64KB; [0..3] reused as cred
  __shared__ float rstat[32][9];                             // pad: avoid 8-way bank conflict
  const int f = blockIdx.x;
  const int fp = (f & 7) * 256 + (f >> 3);
  const int bh = fp >> 5;
  const int l0 = (fp & 31) * 32;
  const int tid = threadIdx.x;
  const int lane = tid & 63, wave = tid >> 6;
  const int hi = lane >> 5, ln = lane & 31;
  const bf16_t* qb = q + (size_t)bh * 1024 * 64;
  const bf16_t* kb = k + (size_t)bh * 1024 * 64;
  const bf16_t* vb = vt + (size_t)bh * 64 * 1024;
  const int rbase = wave * 128;
  const int b0 = l0 - rbase + 992;

  bf16x8 qf[4];
#pragma unroll
  for (int kk = 0; kk < 4; ++kk)
    qf[kk] = *reinterpret_cast<const bf16x8*>(&qb[(size_t)(l0 + ln) * 64 + kk * 16 + hi * 8]);

  // T_{-1}: E rows [b0+32, b0+64)
  f32x16 tpre = zero16();
  __builtin_amdgcn_s_setprio(1);
#pragma unroll
  for (int kk = 0; kk < 4; ++kk) {
    bf16x8 e = *reinterpret_cast<const bf16x8*>(
        &E[(size_t)(b0 + 32 + ln) * 64 + kk * 16 + hi * 8]);
    tpre = __builtin_amdgcn_mfma_f32_32x32x16_bf16(qf[kk], e, tpre, 0, 0, 0);
  }
  __builtin_amdgcn_s_setprio(0);

#pragma unroll
  for (int t = 0; t < 4; ++t) {
    const int r0 = rbase + t * 32;
    f32x16 acc = zero16();
    f32x16 tcur = zero16();
    __builtin_amdgcn_s_setprio(1);
#pragma unroll
    for (int kk = 0; kk < 4; ++kk) {
      bf16x8 kf = *reinterpret_cast<const bf16x8*>(
          &kb[(size_t)(r0 + ln) * 64 + kk * 16 + hi * 8]);
      acc = __builtin_amdgcn_mfma_f32_32x32x16_bf16(qf[kk], kf, acc, 0, 0, 0);
      bf16x8 e = *reinterpret_cast<const bf16x8*>(
          &E[(size_t)(b0 - 32 * t + ln) * 64 + kk * 16 + hi * 8]);
      tcur = __builtin_amdgcn_mfma_f32_32x32x16_bf16(qf[kk], e, tcur, 0, 0, 0);
    }
    __builtin_amdgcn_s_setprio(0);
    // provider-merged anti-diagonal gather: one shuffle per reg
#pragma unroll
    for (int reg = 0; reg < 16; ++reg) {
      const int i = ROWMAP(reg);
      const int w = i - ln + 31;
      const int src = (w & 31) + (hi << 5);
      acc[reg] += __shfl((ln >= i) ? tcur[reg] : tpre[reg], src, 64);
    }
    // exp2 fold: exp(x*0.125) = exp2(x*0.1803...); write bf16 strip (unnormalized)
    const int col = t * 32 + ln;
#pragma unroll
    for (int reg = 0; reg < 16; ++reg) {
      const int i = ROWMAP(reg);
      union { bf16_t h; unsigned short u; } cv;
      cv.h = (bf16_t)exp2f(acc[reg] * 0.1803368801f);
      Pbuf[wave][i][((col >> 3) ^ (i & 7)) * 8 + (col & 7)] = cv.u;
    }
    tpre = tcur;
  }

  // ---- rowsum from own strip (same-wave RAW, lgkmcnt only — no barrier) ----
  {
    float s = 0.0f;
#pragma unroll
    for (int g = 0; g < 8; ++g) {
      const int cg = hi * 8 + g;
      bf16x8 pv = *reinterpret_cast<const bf16x8*>(
          &Pbuf[wave][ln][((cg ^ (ln & 7))) * 8]);
#pragma unroll
      for (int e = 0; e < 8; ++e) s += (float)pv[e];
    }
    s += __shfl_xor(s, 32, 64);
    if (hi == 0) rstat[ln][wave] = s;
  }

  // ---- PV before S1: partial ctx over this wave's 128 columns (unnormalized P) ----
  f32x16 pv0 = zero16(), pv1 = zero16();
  __builtin_amdgcn_s_setprio(1);
#pragma unroll
  for (int kk = 0; kk < 8; ++kk) {
    const int ch = kk * 2 + hi;
    bf16x8 pa = *reinterpret_cast<const bf16x8*>(&Pbuf[wave][ln][(ch ^ (ln & 7)) * 8]);
    bf16x8 v0 = *reinterpret_cast<const bf16x8*>(
        &vb[(size_t)ln * 1024 + rbase + kk * 16 + hi * 8]);
    bf16x8 v1 = *reinterpret_cast<const bf16x8*>(
        &vb[(size_t)(32 + ln) * 1024 + rbase + kk * 16 + hi * 8]);
    pv0 = __builtin_amdgcn_mfma_f32_32x32x16_bf16(pa, v0, pv0, 0, 0, 0);
    pv1 = __builtin_amdgcn_mfma_f32_32x32x16_bf16(pa, v1, pv1, 0, 0, 0);
  }
  __builtin_amdgcn_s_setprio(0);

  __syncthreads();  // S1: rstat from all waves visible

  // ---- per-wave inv: lane ln holds 1/rowsum of row ln ----
  float inv;
  {
    float s = 0.0f;
#pragma unroll
    for (int w = 0; w < 8; ++w) s += rstat[ln][w];
    inv = 1.0f / s;
  }

  // ---- probs: re-read bf16 strip, normalize, nt-store float4 ----
  float* pb = probs + ((size_t)bh * 1024 + l0) * 1024;
#pragma unroll
  for (int it = 0; it < 16; ++it) {
    const int r = it * 2 + hi;
    const float invr = __shfl(inv, r, 64);
    const int g = ln >> 1;
    bf16x4 pv = *reinterpret_cast<const bf16x4*>(
        &Pbuf[wave][r][(g ^ (r & 7)) * 8 + (ln & 1) * 4]);
    f32x4v o;
    o[0] = (float)pv[0] * invr; o[1] = (float)pv[1] * invr;
    o[2] = (float)pv[2] * invr; o[3] = (float)pv[3] * invr;
    __builtin_nontemporal_store(
        o, reinterpret_cast<f32x4v*>(&pb[(size_t)r * 1024 + rbase + ln * 4]));
  }

  // ---- ctx reduce across 8 waves (alias Pbuf[0..3] as cred[4][32][64] f32) ----
  float* cred = reinterpret_cast<float*>(&Pbuf[0][0][0]);
  if (wave < 4) {
#pragma unroll
    for (int reg = 0; reg < 16; ++reg) {
      const int i = ROWMAP(reg);
      cred[((size_t)wave * 32 + i) * 64 + ln] = pv0[reg];
      cred[((size_t)wave * 32 + i) * 64 + 32 + ln] = pv1[reg];
    }
  }
  __syncthreads();  // S2: cred writes done
  if (wave >= 4) {
    const int s = wave - 4;
#pragma unroll
    for (int reg = 0; reg < 16; ++reg) {
      const int i = ROWMAP(reg);
      cred[((size_t)s * 32 + i) * 64 + ln] += pv0[reg];
      cred[((size_t)s * 32 + i) * 64 + 32 + ln] += pv1[reg];
    }
  }
  __syncthreads();  // S3: adds done
  {
    const int i = tid >> 4, d0 = (tid & 15) * 4;
    float4 a = *reinterpret_cast<const float4*>(&cred[(size_t)(0 * 32 + i) * 64 + d0]);
#pragma unroll
    for (int s = 1; s < 4; ++s) {
      float4 b = *reinterpret_cast<const float4*>(&cred[(size_t)(s * 32 + i) * 64 + d0]);
      a.x += b.x; a.y += b.y; a.z += b.z; a.w += b.w;
    }
    const float invr = __shfl(inv, i, 64);
    U4B o;
    o.h[0] = (bf16_t)(a.x * invr); o.h[1] = (bf16_t)(a.y * invr);
    o.h[2] = (bf16_t)(a.z * invr); o.h[3] = (bf16_t)(a.w * invr);
    const int b = bh >> 4, h = bh & 15;
    *reinterpret_cast<uint2*>(&ctx[((((size_t)b * 1024) + l0 + i) * 16 + h) * 64 + d0]) = o.u;
  }
}

// ---------------- launch ---------------------------------------------------------
extern "C" void kernel_launch(void* const* d_in, const int* in_sizes, int n_in,
                              void* d_out, int out_size, void* d_ws, size_t ws_size,
                              hipStream_t stream) {
  const float* xq = (const float*)d_in[0];
  const float* xk = (const float*)d_in[1];
  const float* xv = (const float*)d_in[2];
  const float* Wq = (const float*)d_in[3];
  const float* bq = (const float*)d_in[4];
  const float* Wk = (const float*)d_in[5];
  const float* bk = (const float*)d_in[6];
  const float* Wv = (const float*)d_in[7];
  const float* bv = (const float*)d_in[8];
  const float* Wo = (const float*)d_in[9];
  const float* bo = (const float*)d_in[10];
  const float* relE = (const float*)d_in[11];

  char* ws = (char*)d_ws;
  const size_t MB2 = 1u << 21;
  bf16_t* WtQ = (bf16_t*)(ws + 0 * MB2);
  bf16_t* WtK = (bf16_t*)(ws + 1 * MB2);
  bf16_t* WtV = (bf16_t*)(ws + 2 * MB2);
  bf16_t* WtO = (bf16_t*)(ws + 3 * MB2);
  bf16_t* Eb  = (bf16_t*)(ws + 4 * MB2);
  bf16_t* qb  = (bf16_t*)(ws + 4 * MB2 + (1u << 19));
  bf16_t* kb  = qb + (size_t)4 * 16 * 1024 * 64;
  bf16_t* vtb = kb + (size_t)4 * 16 * 1024 * 64;
  bf16_t* ctxb = vtb + (size_t)4 * 16 * 1024 * 64;

  float* outp = (float*)d_out;
  float* probs = outp + (size_t)4 * 1024 * 1024;

  prep_kernel<<<1152, 256, 0, stream>>>(Wq, Wk, Wv, Wo, WtQ, WtK, WtV, WtO,
                                        relE, Eb);
  gemm_qkv_kernel<<<192, 512, 0, stream>>>(xq, xk, xv, WtQ, WtK, WtV,
                                           bq, bk, bv, qb, kb, vtb);
  attn_kernel<<<2048, 512, 0, stream>>>(qb, kb, vtb, Eb, probs, ctxb);
  gemm_o_kernel<<<256, 256, 0, stream>>>(ctxb, WtO, bo, outp);
}